// Round 1
// baseline (3478.267 us; speedup 1.0000x reference)
//
#include <hip/hip_runtime.h>
#include <hip/hip_bf16.h>
#include <math.h>
#include <cstddef>

#define LSEQ 8000
#define EPS 1e-5f

// ---------------- batched transpose: dst[b][c][r] = src[b][r][c] ----------------
__global__ void transpose_batched(const float* __restrict__ src, float* __restrict__ dst,
                                  int R, int C, int batch) {
    size_t total = (size_t)batch * R * C;
    for (size_t idx = (size_t)blockIdx.x * blockDim.x + threadIdx.x; idx < total;
         idx += (size_t)gridDim.x * blockDim.x) {
        size_t b = idx / ((size_t)R * C);
        size_t rem = idx % ((size_t)R * C);
        size_t r = rem / C;
        size_t c = rem % C;
        dst[(b * C + c) * R + r] = src[idx];
    }
}

// ---------------- stats: sum & sumsq per sample (optionally of prelu(dwconv(in))) ----
template<bool DW>
__global__ void stats_kernel(const float* __restrict__ in,  // [4][C][L]
                             const float* __restrict__ dw,  // [C][3] or null
                             const float* __restrict__ pa,  // [C] or null
                             int dil, int C,
                             float* __restrict__ stats)     // [4][2], pre-zeroed
{
    int b = blockIdx.y;
    const float* base = in + (size_t)b * C * LSEQ;
    float s = 0.f, sq = 0.f;
    size_t total = (size_t)C * LSEQ;
    for (size_t idx = (size_t)blockIdx.x * blockDim.x + threadIdx.x; idx < total;
         idx += (size_t)gridDim.x * blockDim.x) {
        float v;
        if (DW) {
            int c = (int)(idx / LSEQ);
            int l = (int)(idx % LSEQ);
            const float* row = base + (size_t)c * LSEQ;
            float x2 = row[l];
            float x1 = (l >= dil) ? row[l - dil] : 0.f;
            float x0 = (l >= 2 * dil) ? row[l - 2 * dil] : 0.f;
            float h = fmaf(dw[c * 3 + 0], x0, fmaf(dw[c * 3 + 1], x1, dw[c * 3 + 2] * x2));
            v = h > 0.f ? h : pa[c] * h;
        } else {
            v = base[idx];
        }
        s += v;
        sq += v * v;
    }
    for (int off = 32; off > 0; off >>= 1) {
        s += __shfl_down(s, off, 64);
        sq += __shfl_down(sq, off, 64);
    }
    __shared__ float red[8][2];
    int wid = threadIdx.x >> 6, lane = threadIdx.x & 63;
    if (lane == 0) { red[wid][0] = s; red[wid][1] = sq; }
    __syncthreads();
    if (threadIdx.x == 0) {
        float ts = 0.f, tq = 0.f;
        int nw = blockDim.x >> 6;
        for (int i = 0; i < nw; i++) { ts += red[i][0]; tq += red[i][1]; }
        atomicAdd(&stats[b * 2 + 0], ts);
        atomicAdd(&stats[b * 2 + 1], tq);
    }
}

// ---------------- fused GEMM ----------------
// out[b][o][l] = sum_c Wt[c][o] * stage(c,l)  (+ res) (-> sigmoid)
// MODE 0: stage = s[c]*in + t[c]              (normalized plain input)
// MODE 1: stage = s[c]*prelu(dwconv(in)) + t[c]
// MODE 2: stage = in                           (identity; expansion)
template<int KTOT, int MM, int MODE, bool HASRES, bool SIG>
__global__ __launch_bounds__(256)
void gemm_kernel(const float* __restrict__ in,    // [4][KTOT][L]
                 const float* __restrict__ Wt,    // [KTOT][MM] (transposed weights)
                 const float* __restrict__ stats, // [4][2]
                 const float* __restrict__ g,     // [KTOT]
                 const float* __restrict__ bta,   // [KTOT]
                 const float* __restrict__ dw,    // [KTOT][3]
                 const float* __restrict__ pa,    // [KTOT]
                 int dil,
                 const float* __restrict__ res,   // [4][MM][L]
                 float* __restrict__ outp)        // [4][MM][L]
{
    constexpr int NCHUNK = KTOT / 128;
    __shared__ float hs[128 * 33];
    __shared__ float s_l[(MODE != 2) ? KTOT : 1];
    __shared__ float t_l[(MODE != 2) ? KTOT : 1];
    __shared__ float dw_l[(MODE == 1) ? KTOT * 3 : 1];
    __shared__ float pa_l[(MODE == 1) ? KTOT : 1];

    int tid = threadIdx.x;
    int b = blockIdx.z;
    int l0 = blockIdx.x * 32;
    int obase = blockIdx.y * 128;

    if (MODE != 2) {
        float sum = stats[b * 2 + 0], sumsq = stats[b * 2 + 1];
        float denom = 1.f / ((float)KTOT * (float)LSEQ);
        float m = sum * denom;
        float var = sumsq * denom - m * m;
        float rs = rsqrtf(var + EPS);
        for (int c = tid; c < KTOT; c += 256) {
            float sc = rs * g[c];
            s_l[c] = sc;
            t_l[c] = bta[c] - m * sc;
            if (MODE == 1) {
                dw_l[c * 3 + 0] = dw[c * 3 + 0];
                dw_l[c * 3 + 1] = dw[c * 3 + 1];
                dw_l[c * 3 + 2] = dw[c * 3 + 2];
                pa_l[c] = pa[c];
            }
        }
    }

    int og = tid >> 5;
    int l = tid & 31;
    float acc[16];
#pragma unroll
    for (int j = 0; j < 16; j++) acc[j] = 0.f;

    for (int kc = 0; kc < NCHUNK; kc++) {
        int k0 = kc * 128;
        __syncthreads(); // prev main-loop reads done; also covers s_l/t_l init
#pragma unroll
        for (int t = 0; t < 16; t++) {
            int idx = tid + t * 256;
            int c = idx >> 5;
            int ll = idx & 31;
            int gl = l0 + ll;
            const float* row = in + ((size_t)b * KTOT + k0 + c) * LSEQ;
            float v;
            if (MODE == 1) {
                float x2 = row[gl];
                float x1 = (gl >= dil) ? row[gl - dil] : 0.f;
                float x0 = (gl >= 2 * dil) ? row[gl - 2 * dil] : 0.f;
                int cc = k0 + c;
                float h = fmaf(dw_l[cc * 3 + 0], x0, fmaf(dw_l[cc * 3 + 1], x1, dw_l[cc * 3 + 2] * x2));
                h = h > 0.f ? h : pa_l[cc] * h;
                v = fmaf(s_l[cc], h, t_l[cc]);
            } else if (MODE == 0) {
                v = fmaf(s_l[k0 + c], row[gl], t_l[k0 + c]);
            } else {
                v = row[gl];
            }
            hs[c * 33 + ll] = v;
        }
        __syncthreads();

        const float* wbase = Wt + (size_t)k0 * MM + obase + og * 16;
#pragma unroll 4
        for (int c = 0; c < 128; c++) {
            float hv = hs[c * 33 + l];
            const float4* w4 = (const float4*)(wbase + (size_t)c * MM);
            float4 w0 = w4[0], w1 = w4[1], w2 = w4[2], w3 = w4[3];
            acc[0]  = fmaf(w0.x, hv, acc[0]);
            acc[1]  = fmaf(w0.y, hv, acc[1]);
            acc[2]  = fmaf(w0.z, hv, acc[2]);
            acc[3]  = fmaf(w0.w, hv, acc[3]);
            acc[4]  = fmaf(w1.x, hv, acc[4]);
            acc[5]  = fmaf(w1.y, hv, acc[5]);
            acc[6]  = fmaf(w1.z, hv, acc[6]);
            acc[7]  = fmaf(w1.w, hv, acc[7]);
            acc[8]  = fmaf(w2.x, hv, acc[8]);
            acc[9]  = fmaf(w2.y, hv, acc[9]);
            acc[10] = fmaf(w2.z, hv, acc[10]);
            acc[11] = fmaf(w2.w, hv, acc[11]);
            acc[12] = fmaf(w3.x, hv, acc[12]);
            acc[13] = fmaf(w3.y, hv, acc[13]);
            acc[14] = fmaf(w3.z, hv, acc[14]);
            acc[15] = fmaf(w3.w, hv, acc[15]);
        }
    }

    size_t outrow = ((size_t)b * MM + obase + og * 16) * LSEQ + l0 + l;
#pragma unroll
    for (int j = 0; j < 16; j++) {
        float v = acc[j];
        if (HASRES) v += res[outrow + (size_t)j * LSEQ];
        if (SIG) v = 1.f / (1.f + __expf(-v));
        outp[outrow + (size_t)j * LSEQ] = v;
    }
}

extern "C" void kernel_launch(void* const* d_in, const int* in_sizes, int n_in,
                              void* d_out, int out_size, void* d_ws, size_t ws_size,
                              hipStream_t stream) {
    const float* x      = (const float*)d_in[0];
    const float* gn_g   = (const float*)d_in[1];
    const float* gn_b   = (const float*)d_in[2];
    const float* w_comp = (const float*)d_in[3];
    const float* dw_w   = (const float*)d_in[4];
    const float* pr_a   = (const float*)d_in[5];
    const float* tn_g   = (const float*)d_in[6];
    const float* tn_b   = (const float*)d_in[7];
    const float* pw_w   = (const float*)d_in[8];
    const float* w_exp  = (const float*)d_in[9];
    float* out = (float*)d_out;

    const size_t ACT = (size_t)4 * 128 * LSEQ;
    float* bufA  = (float*)d_ws;
    float* bufB  = bufA + ACT;
    float* wct   = bufB + ACT;              // [512][128]
    float* pwt   = wct + 512 * 128;         // 24 x [128][128]
    float* wet   = pwt + 24 * 128 * 128;    // [128][1024]
    float* stats = wet + 128 * 1024;        // [25][4][2]

    hipMemsetAsync(stats, 0, 25 * 4 * 2 * sizeof(float), stream);

    transpose_batched<<<dim3(512), 256, 0, stream>>>(w_comp, wct, 128, 512, 1);
    transpose_batched<<<dim3(512), 256, 0, stream>>>(pw_w, pwt, 128, 128, 24);
    transpose_batched<<<dim3(512), 256, 0, stream>>>(w_exp, wet, 1024, 128, 1);

    // front: GN(x) stats + compression GEMM (GN folded into staging)
    stats_kernel<false><<<dim3(512, 4), 256, 0, stream>>>(x, nullptr, nullptr, 0, 512, stats);
    gemm_kernel<512, 128, 0, false, false><<<dim3(250, 1, 4), 256, 0, stream>>>(
        x, wct, stats, gn_g, gn_b, nullptr, nullptr, 0, nullptr, bufA);

    float* cur = bufA;
    float* nxt = bufB;
    for (int i = 0; i < 24; i++) {
        int dil = 1 << (i & 7);
        float* st = stats + (size_t)(1 + i) * 8;
        stats_kernel<true><<<dim3(256, 4), 256, 0, stream>>>(
            cur, dw_w + (size_t)i * 128 * 3, pr_a + (size_t)i * 128, dil, 128, st);
        gemm_kernel<128, 128, 1, true, false><<<dim3(250, 1, 4), 256, 0, stream>>>(
            cur, pwt + (size_t)i * 128 * 128, st, tn_g + (size_t)i * 128, tn_b + (size_t)i * 128,
            dw_w + (size_t)i * 128 * 3, pr_a + (size_t)i * 128, dil, cur, nxt);
        float* tmp = cur; cur = nxt; nxt = tmp;
    }

    // back: expansion (128 -> 1024) + sigmoid, straight to d_out
    gemm_kernel<128, 1024, 2, false, true><<<dim3(250, 8, 4), 256, 0, stream>>>(
        cur, wet, nullptr, nullptr, nullptr, nullptr, nullptr, 0, nullptr, out);
}

// Round 2
// 2137.853 us; speedup vs baseline: 1.6270x; 1.6270x over previous
//
#include <hip/hip_runtime.h>
#include <hip/hip_bf16.h>
#include <math.h>
#include <cstddef>

#define LSEQ 8000
#define EPS 1e-5f

// ---------------- batched transpose: dst[b][c][r] = src[b][r][c] ----------------
__global__ void transpose_batched(const float* __restrict__ src, float* __restrict__ dst,
                                  int R, int C, int batch) {
    size_t total = (size_t)batch * R * C;
    for (size_t idx = (size_t)blockIdx.x * blockDim.x + threadIdx.x; idx < total;
         idx += (size_t)gridDim.x * blockDim.x) {
        size_t b = idx / ((size_t)R * C);
        size_t rem = idx % ((size_t)R * C);
        size_t r = rem / C;
        size_t c = rem % C;
        dst[(b * C + c) * R + r] = src[idx];
    }
}

// ---------------- stats: sum & sumsq per sample (optionally of prelu(dwconv(in))) ----
template<bool DW>
__global__ void stats_kernel(const float* __restrict__ in,  // [4][C][L]
                             const float* __restrict__ dw,  // [C][3] or null
                             const float* __restrict__ pa,  // [C] or null
                             int dil, int C,
                             float* __restrict__ stats)     // [4][2], pre-zeroed
{
    int b = blockIdx.y;
    const float* base = in + (size_t)b * C * LSEQ;
    float s = 0.f, sq = 0.f;
    size_t total = (size_t)C * LSEQ;
    for (size_t idx = (size_t)blockIdx.x * blockDim.x + threadIdx.x; idx < total;
         idx += (size_t)gridDim.x * blockDim.x) {
        float v;
        if (DW) {
            int c = (int)(idx / LSEQ);
            int l = (int)(idx % LSEQ);
            const float* row = base + (size_t)c * LSEQ;
            float x2 = row[l];
            float x1 = (l >= dil) ? row[l - dil] : 0.f;
            float x0 = (l >= 2 * dil) ? row[l - 2 * dil] : 0.f;
            float h = fmaf(dw[c * 3 + 0], x0, fmaf(dw[c * 3 + 1], x1, dw[c * 3 + 2] * x2));
            v = h > 0.f ? h : pa[c] * h;
        } else {
            v = base[idx];
        }
        s += v;
        sq += v * v;
    }
    for (int off = 32; off > 0; off >>= 1) {
        s += __shfl_down(s, off, 64);
        sq += __shfl_down(sq, off, 64);
    }
    __shared__ float red[8][2];
    int wid = threadIdx.x >> 6, lane = threadIdx.x & 63;
    if (lane == 0) { red[wid][0] = s; red[wid][1] = sq; }
    __syncthreads();
    if (threadIdx.x == 0) {
        float ts = 0.f, tq = 0.f;
        int nw = blockDim.x >> 6;
        for (int i = 0; i < nw; i++) { ts += red[i][0]; tq += red[i][1]; }
        atomicAdd(&stats[b * 2 + 0], ts);
        atomicAdd(&stats[b * 2 + 1], tq);
    }
}

// ---------------- fused GEMM, register-blocked ----------------
// out[b][o][l] = sum_c Wt[c][o] * stage(c,l)  (+ res) (-> sigmoid)
// MODE 0: stage = s[c]*in + t[c]   MODE 1: stage = s[c]*prelu(dwconv(in)) + t[c]
// MODE 2: stage = in
// Tile: BM=128 outs x BN=64 cols. 256 threads = 16 og (8 outs) x 16 cg (4 cols).
template<int KTOT, int MM, int MODE, bool HASRES, bool SIG>
__global__ __launch_bounds__(256)
void gemm_kernel(const float* __restrict__ in,    // [4][KTOT][L]
                 const float* __restrict__ Wt,    // [KTOT][MM] (transposed weights)
                 const float* __restrict__ stats, // [4][2]
                 const float* __restrict__ g,     // [KTOT]
                 const float* __restrict__ bta,   // [KTOT]
                 const float* __restrict__ dw,    // [KTOT][3]
                 const float* __restrict__ pa,    // [KTOT]
                 int dil,
                 const float* __restrict__ res,   // [4][MM][L]
                 float* __restrict__ outp)        // [4][MM][L]
{
    constexpr int NCHUNK = KTOT / 128;
    __shared__ float hs[128 * 64];
    __shared__ float s_l[(MODE != 2) ? KTOT : 1];
    __shared__ float t_l[(MODE != 2) ? KTOT : 1];
    __shared__ float dw_l[(MODE == 1) ? KTOT * 3 : 1];
    __shared__ float pa_l[(MODE == 1) ? KTOT : 1];

    int tid = threadIdx.x;
    int b = blockIdx.z;
    int l0 = blockIdx.x * 64;
    int obase = blockIdx.y * 128;

    if (MODE != 2) {
        float sum = stats[b * 2 + 0], sumsq = stats[b * 2 + 1];
        float denom = 1.f / ((float)KTOT * (float)LSEQ);
        float m = sum * denom;
        float var = sumsq * denom - m * m;
        float rs = rsqrtf(var + EPS);
        for (int c = tid; c < KTOT; c += 256) {
            float sc = rs * g[c];
            s_l[c] = sc;
            t_l[c] = bta[c] - m * sc;
            if (MODE == 1) {
                dw_l[c * 3 + 0] = dw[c * 3 + 0];
                dw_l[c * 3 + 1] = dw[c * 3 + 1];
                dw_l[c * 3 + 2] = dw[c * 3 + 2];
                pa_l[c] = pa[c];
            }
        }
    }

    int og = tid >> 4;       // 16 groups of 8 outputs
    int cg = tid & 15;       // 16 groups of 4 columns
    float acc[8][4];
#pragma unroll
    for (int j = 0; j < 8; j++)
#pragma unroll
        for (int i = 0; i < 4; i++) acc[j][i] = 0.f;

    for (int kc = 0; kc < NCHUNK; kc++) {
        int k0 = kc * 128;
        __syncthreads(); // prev compute reads done; also covers table init
        if (MODE == 1) {
            // scalar staging with dwconv taps, coalesced along l
#pragma unroll
            for (int t = 0; t < 32; t++) {
                int idx = tid + t * 256;
                int c = idx >> 6;
                int ll = idx & 63;
                int gl = l0 + ll;
                const float* row = in + ((size_t)b * KTOT + k0 + c) * LSEQ;
                float x2 = row[gl];
                float x1 = (gl >= dil) ? row[gl - dil] : 0.f;
                float x0 = (gl >= 2 * dil) ? row[gl - 2 * dil] : 0.f;
                int cc = k0 + c;
                float h = fmaf(dw_l[cc * 3 + 0], x0, fmaf(dw_l[cc * 3 + 1], x1, dw_l[cc * 3 + 2] * x2));
                h = h > 0.f ? h : pa_l[cc] * h;
                hs[c * 64 + ll] = fmaf(s_l[cc], h, t_l[cc]);
            }
        } else {
            // vectorized float4 staging
#pragma unroll
            for (int t = 0; t < 8; t++) {
                int idx = tid + t * 256;
                int c = idx >> 4;
                int l4 = idx & 15;
                const float* row = in + ((size_t)b * KTOT + k0 + c) * LSEQ + l0 + l4 * 4;
                float4 v = *(const float4*)row;
                if (MODE == 0) {
                    float sc = s_l[k0 + c], tc = t_l[k0 + c];
                    v.x = fmaf(sc, v.x, tc);
                    v.y = fmaf(sc, v.y, tc);
                    v.z = fmaf(sc, v.z, tc);
                    v.w = fmaf(sc, v.w, tc);
                }
                *(float4*)&hs[c * 64 + l4 * 4] = v;
            }
        }
        __syncthreads();

        const float* wbase = Wt + (size_t)k0 * MM + obase + og * 8;
#pragma unroll 4
        for (int c = 0; c < 128; c++) {
            const float* wr = wbase + (size_t)c * MM;
            float4 w0 = *(const float4*)(wr);
            float4 w1 = *(const float4*)(wr + 4);
            float4 a = *(const float4*)&hs[c * 64 + cg * 4];
            float wv[8] = {w0.x, w0.y, w0.z, w0.w, w1.x, w1.y, w1.z, w1.w};
            float av[4] = {a.x, a.y, a.z, a.w};
#pragma unroll
            for (int j = 0; j < 8; j++)
#pragma unroll
                for (int i = 0; i < 4; i++)
                    acc[j][i] = fmaf(wv[j], av[i], acc[j][i]);
        }
    }

    // epilogue: rows obase + og*8 + j, cols l0 + cg*4 .. +3
#pragma unroll
    for (int j = 0; j < 8; j++) {
        size_t row = ((size_t)b * MM + obase + og * 8 + j) * LSEQ + l0 + cg * 4;
        float4 v = {acc[j][0], acc[j][1], acc[j][2], acc[j][3]};
        if (HASRES) {
            float4 r = *(const float4*)(res + row);
            v.x += r.x; v.y += r.y; v.z += r.z; v.w += r.w;
        }
        if (SIG) {
            v.x = 1.f / (1.f + __expf(-v.x));
            v.y = 1.f / (1.f + __expf(-v.y));
            v.z = 1.f / (1.f + __expf(-v.z));
            v.w = 1.f / (1.f + __expf(-v.w));
        }
        *(float4*)(outp + row) = v;
    }
}

extern "C" void kernel_launch(void* const* d_in, const int* in_sizes, int n_in,
                              void* d_out, int out_size, void* d_ws, size_t ws_size,
                              hipStream_t stream) {
    const float* x      = (const float*)d_in[0];
    const float* gn_g   = (const float*)d_in[1];
    const float* gn_b   = (const float*)d_in[2];
    const float* w_comp = (const float*)d_in[3];
    const float* dw_w   = (const float*)d_in[4];
    const float* pr_a   = (const float*)d_in[5];
    const float* tn_g   = (const float*)d_in[6];
    const float* tn_b   = (const float*)d_in[7];
    const float* pw_w   = (const float*)d_in[8];
    const float* w_exp  = (const float*)d_in[9];
    float* out = (float*)d_out;

    const size_t ACT = (size_t)4 * 128 * LSEQ;
    float* bufA  = (float*)d_ws;
    float* bufB  = bufA + ACT;
    float* wct   = bufB + ACT;              // [512][128]
    float* pwt   = wct + 512 * 128;         // 24 x [128][128]
    float* wet   = pwt + 24 * 128 * 128;    // [128][1024]
    float* stats = wet + 128 * 1024;        // [25][4][2]

    hipMemsetAsync(stats, 0, 25 * 4 * 2 * sizeof(float), stream);

    transpose_batched<<<dim3(512), 256, 0, stream>>>(w_comp, wct, 128, 512, 1);
    transpose_batched<<<dim3(512), 256, 0, stream>>>(pw_w, pwt, 128, 128, 24);
    transpose_batched<<<dim3(512), 256, 0, stream>>>(w_exp, wet, 1024, 128, 1);

    // front: GN(x) stats + compression GEMM (GN folded into staging)
    stats_kernel<false><<<dim3(512, 4), 256, 0, stream>>>(x, nullptr, nullptr, 0, 512, stats);
    gemm_kernel<512, 128, 0, false, false><<<dim3(125, 1, 4), 256, 0, stream>>>(
        x, wct, stats, gn_g, gn_b, nullptr, nullptr, 0, nullptr, bufA);

    float* cur = bufA;
    float* nxt = bufB;
    for (int i = 0; i < 24; i++) {
        int dil = 1 << (i & 7);
        float* st = stats + (size_t)(1 + i) * 8;
        stats_kernel<true><<<dim3(256, 4), 256, 0, stream>>>(
            cur, dw_w + (size_t)i * 128 * 3, pr_a + (size_t)i * 128, dil, 128, st);
        gemm_kernel<128, 128, 1, true, false><<<dim3(125, 1, 4), 256, 0, stream>>>(
            cur, pwt + (size_t)i * 128 * 128, st, tn_g + (size_t)i * 128, tn_b + (size_t)i * 128,
            dw_w + (size_t)i * 128 * 3, pr_a + (size_t)i * 128, dil, cur, nxt);
        float* tmp = cur; cur = nxt; nxt = tmp;
    }

    // back: expansion (128 -> 1024) + sigmoid, straight to d_out
    gemm_kernel<128, 1024, 2, false, true><<<dim3(125, 8, 4), 256, 0, stream>>>(
        cur, wet, nullptr, nullptr, nullptr, nullptr, nullptr, 0, nullptr, out);
}

// Round 3
// 1740.818 us; speedup vs baseline: 1.9981x; 1.2281x over previous
//
#include <hip/hip_runtime.h>
#include <hip/hip_bf16.h>
#include <math.h>
#include <cstddef>

#define LSEQ 8000
#define EPS 1e-5f

typedef unsigned short ushort_t;
typedef __attribute__((ext_vector_type(8))) short s16x8;   // 8 bf16 = 4 VGPR
typedef __attribute__((ext_vector_type(4))) float f32x4;   // MFMA C/D

__device__ __forceinline__ ushort_t f2bf(float f) {
    union { float f; unsigned u; } x; x.f = f;
    unsigned r = x.u + 0x7FFFu + ((x.u >> 16) & 1u);   // round-to-nearest-even
    return (ushort_t)(r >> 16);
}

// ---------------- fp32 -> bf16 elementwise convert (weights) ----------------
__global__ void cvt_bf16_kernel(const float* __restrict__ src, ushort_t* __restrict__ dst, int n) {
    for (int i = blockIdx.x * blockDim.x + threadIdx.x; i < n; i += gridDim.x * blockDim.x)
        dst[i] = f2bf(src[i]);
}

// ---------------- stats: sum & sumsq per sample (optionally of prelu(dwconv(in))) ----
template<bool DW>
__global__ void stats_kernel(const float* __restrict__ in,  // [4][C][L]
                             const float* __restrict__ dw,  // [C][3] or null
                             const float* __restrict__ pa,  // [C] or null
                             int dil, int C,
                             float* __restrict__ stats)     // [4][2], pre-zeroed
{
    int b = blockIdx.y;
    const float* base = in + (size_t)b * C * LSEQ;
    float s = 0.f, sq = 0.f;
    size_t total = (size_t)C * LSEQ;
    for (size_t idx = (size_t)blockIdx.x * blockDim.x + threadIdx.x; idx < total;
         idx += (size_t)gridDim.x * blockDim.x) {
        float v;
        if (DW) {
            int c = (int)(idx / LSEQ);
            int l = (int)(idx % LSEQ);
            const float* row = base + (size_t)c * LSEQ;
            float x2 = row[l];
            float x1 = (l >= dil) ? row[l - dil] : 0.f;
            float x0 = (l >= 2 * dil) ? row[l - 2 * dil] : 0.f;
            float h = fmaf(dw[c * 3 + 0], x0, fmaf(dw[c * 3 + 1], x1, dw[c * 3 + 2] * x2));
            v = h > 0.f ? h : pa[c] * h;
        } else {
            v = base[idx];
        }
        s += v;
        sq += v * v;
    }
    for (int off = 32; off > 0; off >>= 1) {
        s += __shfl_down(s, off, 64);
        sq += __shfl_down(sq, off, 64);
    }
    __shared__ float red[8][2];
    int wid = threadIdx.x >> 6, lane = threadIdx.x & 63;
    if (lane == 0) { red[wid][0] = s; red[wid][1] = sq; }
    __syncthreads();
    if (threadIdx.x == 0) {
        float ts = 0.f, tq = 0.f;
        int nw = blockDim.x >> 6;
        for (int i = 0; i < nw; i++) { ts += red[i][0]; tq += red[i][1]; }
        atomicAdd(&stats[b * 2 + 0], ts);
        atomicAdd(&stats[b * 2 + 1], tq);
    }
}

// ---------------- fused MFMA GEMM ----------------
// out[b][o][l] = sum_c W[o][c] * stage(c,l)  (+ res) (-> sigmoid)
// MODE 0: stage = s[c]*in + t[c]   MODE 1: stage = s[c]*prelu(dwconv(in)) + t[c]
// MODE 2: stage = in
// Tile: 128 rows x 64 cols, 4 waves (2 row-halves x 2 col-halves).
// Wave: 4 rfrag x 2 cfrag of 16x16, K-steps of 32 via mfma_f32_16x16x32_bf16.
// H staged fp32 in LDS with XOR granule swizzle; bf16 conversion at frag read.
template<int KTOT, int MM, int MODE, bool HASRES, bool SIG>
__global__ __launch_bounds__(256)
void gemm_mfma(const float* __restrict__ in,      // [4][KTOT][L] fp32
               const ushort_t* __restrict__ Wb,   // [MM][KTOT] bf16 row-major
               const float* __restrict__ stats,   // [4][2]
               const float* __restrict__ g,       // [KTOT]
               const float* __restrict__ bta,     // [KTOT]
               const float* __restrict__ dw,      // [KTOT][3]
               const float* __restrict__ pa,      // [KTOT]
               int dil,
               const float* __restrict__ res,     // [4][MM][L]
               float* __restrict__ outp)          // [4][MM][L]
{
    constexpr int NCHUNK = KTOT / 128;
    __shared__ float hs[128 * 64];                 // one 128-k chunk x 64 cols, swizzled
    __shared__ float s_l[(MODE != 2) ? KTOT : 1];
    __shared__ float t_l[(MODE != 2) ? KTOT : 1];
    __shared__ float dw_l[(MODE == 1) ? KTOT * 3 : 1];
    __shared__ float pa_l[(MODE == 1) ? KTOT : 1];

    int tid = threadIdx.x;
    int b = blockIdx.z;
    int l0 = blockIdx.x * 64;
    int obase = blockIdx.y * 128;

    if (MODE != 2) {
        float sum = stats[b * 2 + 0], sumsq = stats[b * 2 + 1];
        float denom = 1.f / ((float)KTOT * (float)LSEQ);
        float m = sum * denom;
        float var = sumsq * denom - m * m;
        float rs = rsqrtf(var + EPS);
        for (int c = tid; c < KTOT; c += 256) {
            float sc = rs * g[c];
            s_l[c] = sc;
            t_l[c] = bta[c] - m * sc;
            if (MODE == 1) {
                dw_l[c * 3 + 0] = dw[c * 3 + 0];
                dw_l[c * 3 + 1] = dw[c * 3 + 1];
                dw_l[c * 3 + 2] = dw[c * 3 + 2];
                pa_l[c] = pa[c];
            }
        }
    }

    int wave = tid >> 6;
    int lane = tid & 63;
    int lg = lane >> 4;        // k-group 0..3
    int lr = lane & 15;        // row (A) / col (B) within fragment
    int rowoff = (wave >> 1) * 64;   // 0 / 64
    int coloff = (wave & 1) * 32;    // 0 / 32

    f32x4 acc[4][2];
#pragma unroll
    for (int rf = 0; rf < 4; rf++)
#pragma unroll
        for (int cf = 0; cf < 2; cf++)
            acc[rf][cf] = (f32x4){0.f, 0.f, 0.f, 0.f};

    for (int kc = 0; kc < NCHUNK; kc++) {
        int k0 = kc * 128;
        __syncthreads(); // prev compute done reading hs; also covers table init
        if (MODE == 1) {
            // scalar staging with dwconv taps, coalesced along l
#pragma unroll
            for (int t = 0; t < 32; t++) {
                int idx = tid + t * 256;
                int c = idx >> 6;
                int ll = idx & 63;
                int gl = l0 + ll;
                const float* row = in + ((size_t)b * KTOT + k0 + c) * LSEQ;
                float x2 = row[gl];
                float x1 = (gl >= dil) ? row[gl - dil] : 0.f;
                float x0 = (gl >= 2 * dil) ? row[gl - 2 * dil] : 0.f;
                int cc = k0 + c;
                float h = fmaf(dw_l[cc * 3 + 0], x0, fmaf(dw_l[cc * 3 + 1], x1, dw_l[cc * 3 + 2] * x2));
                h = h > 0.f ? h : pa_l[cc] * h;
                int key = (c & 7) ^ (((c >> 3) & 3) << 2);
                hs[c * 64 + (((ll >> 2) ^ key) << 2) + (ll & 3)] = fmaf(s_l[cc], h, t_l[cc]);
            }
        } else {
            // vectorized float4 staging
#pragma unroll
            for (int t = 0; t < 8; t++) {
                int idx = tid + t * 256;
                int c = idx >> 4;
                int l4 = idx & 15;
                const float* row = in + ((size_t)b * KTOT + k0 + c) * LSEQ + l0 + l4 * 4;
                float4 v = *(const float4*)row;
                if (MODE == 0) {
                    float sc = s_l[k0 + c], tc = t_l[k0 + c];
                    v.x = fmaf(sc, v.x, tc);
                    v.y = fmaf(sc, v.y, tc);
                    v.z = fmaf(sc, v.z, tc);
                    v.w = fmaf(sc, v.w, tc);
                }
                int key = (c & 7) ^ (((c >> 3) & 3) << 2);
                *(float4*)&hs[c * 64 + ((l4 ^ key) << 2)] = v;
            }
        }
        __syncthreads();

        int qbase = (coloff >> 2);   // col>>2 base offset (multiple of 4)
#pragma unroll
        for (int ks = 0; ks < 4; ks++) {
            // A fragments: lane holds W[row = base+rf*16+lr][k = ks*32 + lg*8 + j]
            s16x8 afr[4];
#pragma unroll
            for (int rf = 0; rf < 4; rf++) {
                int row = obase + rowoff + rf * 16 + lr;
                afr[rf] = *(const s16x8*)(Wb + (size_t)row * KTOT + k0 + ks * 32 + lg * 8);
            }
#pragma unroll
            for (int cf = 0; cf < 2; cf++) {
                int col = coloff + cf * 16 + lr;
                int q = col >> 2, sub = col & 3;
                s16x8 bfr;
#pragma unroll
                for (int j = 0; j < 8; j++) {
                    int k = ks * 32 + lg * 8 + j;
                    int key = (k & 7) ^ (((k >> 3) & 3) << 2);
                    float v = hs[k * 64 + ((q ^ key) << 2) + sub];
                    bfr[j] = (short)f2bf(v);
                }
#pragma unroll
                for (int rf = 0; rf < 4; rf++)
                    acc[rf][cf] = __builtin_amdgcn_mfma_f32_16x16x32_bf16(afr[rf], bfr, acc[rf][cf], 0, 0, 0);
            }
        }
    }

    // epilogue: D[row = lg*4 + r][col = lr] per fragment
#pragma unroll
    for (int rf = 0; rf < 4; rf++) {
#pragma unroll
        for (int cf = 0; cf < 2; cf++) {
#pragma unroll
            for (int r = 0; r < 4; r++) {
                int row = obase + rowoff + rf * 16 + lg * 4 + r;
                int col = l0 + coloff + cf * 16 + lr;
                size_t idx = ((size_t)b * MM + row) * LSEQ + col;
                float v = acc[rf][cf][r];
                if (HASRES) v += res[idx];
                if (SIG) v = 1.f / (1.f + __expf(-v));
                outp[idx] = v;
            }
        }
    }
}

extern "C" void kernel_launch(void* const* d_in, const int* in_sizes, int n_in,
                              void* d_out, int out_size, void* d_ws, size_t ws_size,
                              hipStream_t stream) {
    const float* x      = (const float*)d_in[0];
    const float* gn_g   = (const float*)d_in[1];
    const float* gn_b   = (const float*)d_in[2];
    const float* w_comp = (const float*)d_in[3];
    const float* dw_w   = (const float*)d_in[4];
    const float* pr_a   = (const float*)d_in[5];
    const float* tn_g   = (const float*)d_in[6];
    const float* tn_b   = (const float*)d_in[7];
    const float* pw_w   = (const float*)d_in[8];
    const float* w_exp  = (const float*)d_in[9];
    float* out = (float*)d_out;

    const size_t ACT = (size_t)4 * 128 * LSEQ;
    float* bufA = (float*)d_ws;
    float* bufB = bufA + ACT;
    ushort_t* wcb = (ushort_t*)(bufB + ACT);        // [128][512] bf16 (orig layout)
    ushort_t* pwb = wcb + 128 * 512;                // 24 x [128][128] bf16
    ushort_t* web = pwb + 24 * 128 * 128;           // [1024][128] bf16
    float* stats = (float*)(web + 1024 * 128);      // [25][4][2]

    hipMemsetAsync(stats, 0, 25 * 4 * 2 * sizeof(float), stream);

    cvt_bf16_kernel<<<dim3(256), 256, 0, stream>>>(w_comp, wcb, 128 * 512);
    cvt_bf16_kernel<<<dim3(512), 256, 0, stream>>>(pw_w, pwb, 24 * 128 * 128);
    cvt_bf16_kernel<<<dim3(256), 256, 0, stream>>>(w_exp, web, 1024 * 128);

    // front: GN(x) stats + compression GEMM (GN folded into staging)
    stats_kernel<false><<<dim3(512, 4), 256, 0, stream>>>(x, nullptr, nullptr, 0, 512, stats);
    gemm_mfma<512, 128, 0, false, false><<<dim3(125, 1, 4), 256, 0, stream>>>(
        x, wcb, stats, gn_g, gn_b, nullptr, nullptr, 0, nullptr, bufA);

    float* cur = bufA;
    float* nxt = bufB;
    for (int i = 0; i < 24; i++) {
        int dil = 1 << (i & 7);
        float* st = stats + (size_t)(1 + i) * 8;
        stats_kernel<true><<<dim3(256, 4), 256, 0, stream>>>(
            cur, dw_w + (size_t)i * 128 * 3, pr_a + (size_t)i * 128, dil, 128, st);
        gemm_mfma<128, 128, 1, true, false><<<dim3(125, 1, 4), 256, 0, stream>>>(
            cur, pwb + (size_t)i * 128 * 128, st, tn_g + (size_t)i * 128, tn_b + (size_t)i * 128,
            dw_w + (size_t)i * 128 * 3, pr_a + (size_t)i * 128, dil, cur, nxt);
        float* tmp = cur; cur = nxt; nxt = tmp;
    }

    // back: expansion (128 -> 1024) + sigmoid, straight to d_out
    gemm_mfma<128, 1024, 2, false, true><<<dim3(125, 8, 4), 256, 0, stream>>>(
        cur, web, nullptr, nullptr, nullptr, nullptr, nullptr, 0, nullptr, out);
}

// Round 4
// 1567.142 us; speedup vs baseline: 2.2195x; 1.1108x over previous
//
#include <hip/hip_runtime.h>
#include <hip/hip_bf16.h>
#include <math.h>
#include <cstddef>

#define LSEQ 8000
#define EPS 1e-5f

typedef unsigned short ushort_t;
typedef __attribute__((ext_vector_type(8))) short s16x8;   // 8 bf16 = 4 VGPR
typedef __attribute__((ext_vector_type(4))) float f32x4;   // MFMA C/D

__device__ __forceinline__ ushort_t f2bf(float f) {
    union { float f; unsigned u; } x; x.f = f;
    unsigned r = x.u + 0x7FFFu + ((x.u >> 16) & 1u);   // round-to-nearest-even
    return (ushort_t)(r >> 16);
}
__device__ __forceinline__ float bf2f(ushort_t h) {
    union { unsigned u; float f; } x; x.u = ((unsigned)h) << 16;
    return x.f;
}

// ---------------- fp32 -> (bf16 hi, bf16 lo) split convert (weights) ----------------
__global__ void cvt_split_kernel(const float* __restrict__ src,
                                 ushort_t* __restrict__ hi, ushort_t* __restrict__ lo, int n) {
    for (int i = blockIdx.x * blockDim.x + threadIdx.x; i < n; i += gridDim.x * blockDim.x) {
        float v = src[i];
        ushort_t h = f2bf(v);
        hi[i] = h;
        lo[i] = f2bf(v - bf2f(h));
    }
}

// ---------------- stats: sum & sumsq per sample (optionally of prelu(dwconv(in))) ----
// grid: (C, 4). One block per channel per sample; vectorized along L.
template<bool DW>
__global__ __launch_bounds__(256)
void stats_kernel(const float* __restrict__ in,  // [4][C][L]
                  const float* __restrict__ dw,  // [C][3] or null
                  const float* __restrict__ pa,  // [C] or null
                  int dil, int C,
                  float* __restrict__ stats)     // [4][2], pre-zeroed
{
    int b = blockIdx.y;
    int c = blockIdx.x;
    const float* row = in + ((size_t)b * C + c) * LSEQ;
    float d0 = 0.f, d1 = 0.f, d2 = 0.f, aslope = 0.f;
    if (DW) {
        d0 = dw[c * 3 + 0]; d1 = dw[c * 3 + 1]; d2 = dw[c * 3 + 2];
        aslope = pa[c];
    }
    float s = 0.f, sq = 0.f;
    for (int l4 = threadIdx.x * 4; l4 < LSEQ; l4 += 256 * 4) {
        float4 x2 = *(const float4*)(row + l4);
        float v0, v1, v2, v3;
        if (DW) {
            float x1a[4], x0a[4];
            if (dil >= 4 && l4 >= 2 * dil) {
                float4 t1 = *(const float4*)(row + l4 - dil);
                float4 t0 = *(const float4*)(row + l4 - 2 * dil);
                x1a[0] = t1.x; x1a[1] = t1.y; x1a[2] = t1.z; x1a[3] = t1.w;
                x0a[0] = t0.x; x0a[1] = t0.y; x0a[2] = t0.z; x0a[3] = t0.w;
            } else {
#pragma unroll
                for (int j = 0; j < 4; j++) {
                    int l = l4 + j;
                    x1a[j] = (l >= dil) ? row[l - dil] : 0.f;
                    x0a[j] = (l >= 2 * dil) ? row[l - 2 * dil] : 0.f;
                }
            }
            float xa[4] = {x2.x, x2.y, x2.z, x2.w};
#pragma unroll
            for (int j = 0; j < 4; j++) {
                float h = fmaf(d0, x0a[j], fmaf(d1, x1a[j], d2 * xa[j]));
                h = h > 0.f ? h : aslope * h;
                xa[j] = h;
            }
            v0 = xa[0]; v1 = xa[1]; v2 = xa[2]; v3 = xa[3];
        } else {
            v0 = x2.x; v1 = x2.y; v2 = x2.z; v3 = x2.w;
        }
        s += v0 + v1 + v2 + v3;
        sq += v0 * v0 + v1 * v1 + v2 * v2 + v3 * v3;
    }
    for (int off = 32; off > 0; off >>= 1) {
        s += __shfl_down(s, off, 64);
        sq += __shfl_down(sq, off, 64);
    }
    __shared__ float red[4][2];
    int wid = threadIdx.x >> 6, lane = threadIdx.x & 63;
    if (lane == 0) { red[wid][0] = s; red[wid][1] = sq; }
    __syncthreads();
    if (threadIdx.x == 0) {
        float ts = red[0][0] + red[1][0] + red[2][0] + red[3][0];
        float tq = red[0][1] + red[1][1] + red[2][1] + red[3][1];
        atomicAdd(&stats[b * 2 + 0], ts);
        atomicAdd(&stats[b * 2 + 1], tq);
    }
}

// ---------------- fused MFMA GEMM, split-bf16 (3-term) ----------------
// out[b][o][l] = sum_c W[o][c] * stage(c,l)  (+ res) (-> sigmoid)
// MODE 0: stage = s[c]*in + t[c]   MODE 1: stage = s[c]*prelu(dwconv(in)) + t[c]
// MODE 2: stage = in
// Tile: 128 rows x 64 cols, 4 waves (2 row-halves x 2 col-halves).
// H staged bf16 hi/lo in LDS, layout [col][k] with gk^(col&7) granule swizzle
// so B fragments are single ds_read_b128.
template<int KTOT, int MM, int MODE, bool HASRES, bool SIG>
__global__ __launch_bounds__(256)
void gemm_mfma(const float* __restrict__ in,      // [4][KTOT][L] fp32
               const ushort_t* __restrict__ WbH,  // [MM][KTOT] bf16 hi
               const ushort_t* __restrict__ WbL,  // [MM][KTOT] bf16 lo
               const float* __restrict__ stats,   // [4][2]
               const float* __restrict__ g,       // [KTOT]
               const float* __restrict__ bta,     // [KTOT]
               const float* __restrict__ dw,      // [KTOT][3]
               const float* __restrict__ pa,      // [KTOT]
               int dil,
               const float* __restrict__ res,     // [4][MM][L]
               float* __restrict__ outp)          // [4][MM][L]
{
    constexpr int NCHUNK = KTOT / 128;
    __shared__ ushort_t hsH[64 * 128];   // [col][k] swizzled, 16 KB
    __shared__ ushort_t hsL[64 * 128];
    __shared__ float s_l[(MODE != 2) ? KTOT : 1];
    __shared__ float t_l[(MODE != 2) ? KTOT : 1];
    __shared__ float dw_l[(MODE == 1) ? KTOT * 3 : 1];
    __shared__ float pa_l[(MODE == 1) ? KTOT : 1];

    int tid = threadIdx.x;
    int b = blockIdx.z;
    int l0 = blockIdx.x * 64;
    int obase = blockIdx.y * 128;

    if (MODE != 2) {
        float sum = stats[b * 2 + 0], sumsq = stats[b * 2 + 1];
        float denom = 1.f / ((float)KTOT * (float)LSEQ);
        float m = sum * denom;
        float var = sumsq * denom - m * m;
        float rs = rsqrtf(var + EPS);
        for (int c = tid; c < KTOT; c += 256) {
            float sc = rs * g[c];
            s_l[c] = sc;
            t_l[c] = bta[c] - m * sc;
            if (MODE == 1) {
                dw_l[c * 3 + 0] = dw[c * 3 + 0];
                dw_l[c * 3 + 1] = dw[c * 3 + 1];
                dw_l[c * 3 + 2] = dw[c * 3 + 2];
                pa_l[c] = pa[c];
            }
        }
    }

    int wave = tid >> 6;
    int lane = tid & 63;
    int lg = lane >> 4;              // k-group 0..3
    int lr = lane & 15;              // row (A) / col (B) within fragment
    int rowoff = (wave >> 1) * 64;   // 0 / 64
    int coloff = (wave & 1) * 32;    // 0 / 32

    // staging mapping: col = tid&63, this wave covers granules 4w..4w+3
    int scol = tid & 63;
    int sgk0 = (tid >> 6) * 4;
    int sgl = l0 + scol;

    f32x4 acc[4][2];
#pragma unroll
    for (int rf = 0; rf < 4; rf++)
#pragma unroll
        for (int cf = 0; cf < 2; cf++)
            acc[rf][cf] = (f32x4){0.f, 0.f, 0.f, 0.f};

    for (int kc = 0; kc < NCHUNK; kc++) {
        int k0 = kc * 128;
        __syncthreads();   // prev compute done reading hs; also covers table init
        // ---- stage 128 k x 64 cols as bf16 hi/lo ----
#pragma unroll
        for (int gi = 0; gi < 4; gi++) {
            int gk = sgk0 + gi;
            s16x8 hv, lv;
#pragma unroll
            for (int j = 0; j < 8; j++) {
                int cc = k0 + gk * 8 + j;
                const float* row = in + ((size_t)b * KTOT + cc) * LSEQ;
                float v;
                if (MODE == 1) {
                    float x2 = row[sgl];
                    float x1 = (sgl >= dil) ? row[sgl - dil] : 0.f;
                    float x0 = (sgl >= 2 * dil) ? row[sgl - 2 * dil] : 0.f;
                    float h = fmaf(dw_l[cc * 3 + 0], x0,
                              fmaf(dw_l[cc * 3 + 1], x1, dw_l[cc * 3 + 2] * x2));
                    h = h > 0.f ? h : pa_l[cc] * h;
                    v = fmaf(s_l[cc], h, t_l[cc]);
                } else if (MODE == 0) {
                    v = fmaf(s_l[cc], row[sgl], t_l[cc]);
                } else {
                    v = row[sgl];
                }
                ushort_t hb = f2bf(v);
                hv[j] = (short)hb;
                lv[j] = (short)f2bf(v - bf2f(hb));
            }
            int dst = scol * 128 + ((gk ^ (scol & 7)) << 3);
            *(s16x8*)&hsH[dst] = hv;
            *(s16x8*)&hsL[dst] = lv;
        }
        __syncthreads();

        // ---- compute ----
#pragma unroll
        for (int ks = 0; ks < 4; ks++) {
            s16x8 aH[4], aL[4];
#pragma unroll
            for (int rf = 0; rf < 4; rf++) {
                size_t off = (size_t)(obase + rowoff + rf * 16 + lr) * KTOT + k0 + ks * 32 + lg * 8;
                aH[rf] = *(const s16x8*)(WbH + off);
                aL[rf] = *(const s16x8*)(WbL + off);
            }
#pragma unroll
            for (int cf = 0; cf < 2; cf++) {
                int col = coloff + cf * 16 + lr;
                int gk = ks * 4 + lg;
                int src = col * 128 + ((gk ^ (col & 7)) << 3);
                s16x8 bH = *(const s16x8*)&hsH[src];
                s16x8 bL = *(const s16x8*)&hsL[src];
#pragma unroll
                for (int rf = 0; rf < 4; rf++) {
                    acc[rf][cf] = __builtin_amdgcn_mfma_f32_16x16x32_bf16(aH[rf], bH, acc[rf][cf], 0, 0, 0);
                    acc[rf][cf] = __builtin_amdgcn_mfma_f32_16x16x32_bf16(aH[rf], bL, acc[rf][cf], 0, 0, 0);
                    acc[rf][cf] = __builtin_amdgcn_mfma_f32_16x16x32_bf16(aL[rf], bH, acc[rf][cf], 0, 0, 0);
                }
            }
        }
    }

    // epilogue: D[row = lg*4 + r][col = lr] per fragment
#pragma unroll
    for (int rf = 0; rf < 4; rf++) {
#pragma unroll
        for (int cf = 0; cf < 2; cf++) {
#pragma unroll
            for (int r = 0; r < 4; r++) {
                int row = obase + rowoff + rf * 16 + lg * 4 + r;
                int col = l0 + coloff + cf * 16 + lr;
                size_t idx = ((size_t)b * MM + row) * LSEQ + col;
                float v = acc[rf][cf][r];
                if (HASRES) v += res[idx];
                if (SIG) v = 1.f / (1.f + __expf(-v));
                outp[idx] = v;
            }
        }
    }
}

extern "C" void kernel_launch(void* const* d_in, const int* in_sizes, int n_in,
                              void* d_out, int out_size, void* d_ws, size_t ws_size,
                              hipStream_t stream) {
    const float* x      = (const float*)d_in[0];
    const float* gn_g   = (const float*)d_in[1];
    const float* gn_b   = (const float*)d_in[2];
    const float* w_comp = (const float*)d_in[3];
    const float* dw_w   = (const float*)d_in[4];
    const float* pr_a   = (const float*)d_in[5];
    const float* tn_g   = (const float*)d_in[6];
    const float* tn_b   = (const float*)d_in[7];
    const float* pw_w   = (const float*)d_in[8];
    const float* w_exp  = (const float*)d_in[9];
    float* out = (float*)d_out;

    const size_t ACT = (size_t)4 * 128 * LSEQ;
    float* bufA = (float*)d_ws;
    float* bufB = bufA + ACT;
    ushort_t* wcbH = (ushort_t*)(bufB + ACT);       // [128][512] bf16 hi
    ushort_t* wcbL = wcbH + 128 * 512;              // [128][512] bf16 lo
    ushort_t* pwbH = wcbL + 128 * 512;              // 24 x [128][128] hi
    ushort_t* pwbL = pwbH + 24 * 128 * 128;         // 24 x [128][128] lo
    ushort_t* webH = pwbL + 24 * 128 * 128;         // [1024][128] hi
    ushort_t* webL = webH + 1024 * 128;             // [1024][128] lo
    float* stats = (float*)(webL + 1024 * 128);     // [25][4][2]

    hipMemsetAsync(stats, 0, 25 * 4 * 2 * sizeof(float), stream);

    cvt_split_kernel<<<dim3(256), 256, 0, stream>>>(w_comp, wcbH, wcbL, 128 * 512);
    cvt_split_kernel<<<dim3(512), 256, 0, stream>>>(pw_w, pwbH, pwbL, 24 * 128 * 128);
    cvt_split_kernel<<<dim3(256), 256, 0, stream>>>(w_exp, webH, webL, 1024 * 128);

    // front: GN(x) stats + compression GEMM (GN folded into staging)
    stats_kernel<false><<<dim3(512, 4), 256, 0, stream>>>(x, nullptr, nullptr, 0, 512, stats);
    gemm_mfma<512, 128, 0, false, false><<<dim3(125, 1, 4), 256, 0, stream>>>(
        x, wcbH, wcbL, stats, gn_g, gn_b, nullptr, nullptr, 0, nullptr, bufA);

    float* cur = bufA;
    float* nxt = bufB;
    for (int i = 0; i < 24; i++) {
        int dil = 1 << (i & 7);
        float* st = stats + (size_t)(1 + i) * 8;
        stats_kernel<true><<<dim3(128, 4), 256, 0, stream>>>(
            cur, dw_w + (size_t)i * 128 * 3, pr_a + (size_t)i * 128, dil, 128, st);
        gemm_mfma<128, 128, 1, true, false><<<dim3(125, 1, 4), 256, 0, stream>>>(
            cur, pwbH + (size_t)i * 128 * 128, pwbL + (size_t)i * 128 * 128, st,
            tn_g + (size_t)i * 128, tn_b + (size_t)i * 128,
            dw_w + (size_t)i * 128 * 3, pr_a + (size_t)i * 128, dil, cur, nxt);
        float* tmp = cur; cur = nxt; nxt = tmp;
    }

    // back: expansion (128 -> 1024) + sigmoid, straight to d_out
    gemm_mfma<128, 1024, 2, false, true><<<dim3(125, 8, 4), 256, 0, stream>>>(
        cur, webH, webL, nullptr, nullptr, nullptr, nullptr, nullptr, 0, nullptr, out);
}